// Round 4
// baseline (601.453 us; speedup 1.0000x reference)
//
#include <hip/hip_runtime.h>

// Problem constants (from reference module)
constexpr int T    = 8;
constexpr int ROWS = 100000;
constexpr int D    = 128;     // embedding dim
constexpr int B    = 8192;    // bags per table
constexpr int BAGS = T * B;   // 65536 total bags
constexpr int WAVES_PER_BLOCK = 4;   // 256 threads

typedef float v2f __attribute__((ext_vector_type(2)));

// One 64-lane wave per TWO adjacent bags (A = 2*wave, B = 2*wave+1).
//  - Row load: 64 lanes x 8B = 512B = one full row per instruction.
//  - Row base is wave-uniform (v_readlane -> SGPR): saddr-form loads,
//    address math on the scalar unit, ~zero VALU per load.
//  - Two independent accumulation streams -> 64 outstanding loads per wave
//    (the vmcnt ceiling), maximal latency hiding for the L3-served gather.
__global__ __launch_bounds__(256) void emb_bag_pool_kernel(
    const int*   __restrict__ indices,   // [N] int32
    const int*   __restrict__ offsets,   // [T*B+1] int32 (CSR)
    const float* __restrict__ weights,   // [T*ROWS, D] fp32, tables concatenated
    float*       __restrict__ out)       // [B, T*D] fp32
{
    const int lane = threadIdx.x & 63;
    const int wave = blockIdx.x * WAVES_PER_BLOCK + (threadIdx.x >> 6);
    const int segA = wave * 2;
    const int segB = segA + 1;
    if (segA >= BAGS) return;

    // Three CSR offsets via lanes 0..2, distributed to SGPRs.
    const int off3   = offsets[segA + (lane < 2 ? lane : 2)];
    const int startA = __builtin_amdgcn_readlane(off3, 0);
    const int mid    = __builtin_amdgcn_readlane(off3, 1);
    const int endB   = __builtin_amdgcn_readlane(off3, 2);
    const int lenA = mid - startA;
    const int lenB = endB - mid;

    const size_t tbA = (size_t)(segA >> 13) * (size_t)ROWS;  // table start row, bag A
    const size_t tbB = (size_t)(segB >> 13) * (size_t)ROWS;  // table start row, bag B
    const v2f* __restrict__ wv = (const v2f*)weights;        // row r -> wv[r*64 + lane]

    v2f accA = {0.f, 0.f};
    v2f accB = {0.f, 0.f};

    if (lenA == 32 && lenB == 32) {
        // Fast path (workload has uniform bag length 32).
        // Lanes 0..31 hold bag A's indices, lanes 32..63 bag B's.
        const int half = lane >> 5;
        const int l32  = lane & 31;
        const int vidx = indices[(half ? mid : startA) + l32];

        #pragma unroll
        for (int r = 0; r < 32; ++r) {
            const int rowA = __builtin_amdgcn_readlane(vidx, r);       // SGPR
            const int rowB = __builtin_amdgcn_readlane(vidx, 32 + r);  // SGPR
            accA += wv[(tbA + (size_t)rowA) * 64 + lane];
            accB += wv[(tbB + (size_t)rowB) * 64 + lane];
        }
    } else {
        // Generic path: per-row scalar broadcast.
        for (int r = startA; r < mid; ++r) {
            const int row = __builtin_amdgcn_readfirstlane(indices[r]);
            accA += wv[(tbA + (size_t)row) * 64 + lane];
        }
        for (int r = mid; r < endB; ++r) {
            const int row = __builtin_amdgcn_readfirstlane(indices[r]);
            accB += wv[(tbB + (size_t)row) * 64 + lane];
        }
    }

    // out[b, t*D + 2*lane): 64 lanes x 8B = 512B contiguous per bag.
    // Non-temporal: write-once output, keep L2/L3 for the weights table.
    {
        const int tA = segA >> 13, bA = segA & (B - 1);
        v2f* oA = (v2f*)(out + (size_t)bA * (size_t)(T * D) + (size_t)tA * D);
        __builtin_nontemporal_store(accA, oA + lane);

        const int tB = segB >> 13, bB = segB & (B - 1);
        v2f* oB = (v2f*)(out + (size_t)bB * (size_t)(T * D) + (size_t)tB * D);
        __builtin_nontemporal_store(accB, oB + lane);
    }
}

extern "C" void kernel_launch(void* const* d_in, const int* in_sizes, int n_in,
                              void* d_out, int out_size, void* d_ws, size_t ws_size,
                              hipStream_t stream) {
    const int*   indices = (const int*)d_in[0];   // [N]
    const int*   offsets = (const int*)d_in[1];   // [T*B+1]
    const float* weights = (const float*)d_in[2]; // [T*ROWS*D]
    float*       out     = (float*)d_out;         // [B*T*D]

    const int waves = BAGS / 2;                       // 32768 waves, 2 bags each
    const int grid  = waves / WAVES_PER_BLOCK;        // 8192 blocks x 256 threads
    emb_bag_pool_kernel<<<grid, 256, 0, stream>>>(indices, offsets, weights, out);
}